// Round 9
// baseline (4605.791 us; speedup 1.0000x reference)
//
#include <hip/hip_runtime.h>

#define Bz 32
#define Tz 256
#define Ez 256
#define Hz 256
#define Kz 48
#define G4 1024   // 4*H
#define H2 512    // 2*H

typedef __attribute__((ext_vector_type(8))) short short8;
typedef __attribute__((ext_vector_type(4))) float f32x4;
typedef unsigned short ushort_t;
typedef unsigned int uint_t;
typedef unsigned long long ull_t;

__device__ __forceinline__ float bf2f(ushort_t u) {
    unsigned int x = ((unsigned int)u) << 16;
    union { unsigned int i; float f; } c; c.i = x; return c.f;
}
__device__ __forceinline__ ushort_t f2bf(float f) {
    union { float f; unsigned int i; } c; c.f = f;
    unsigned int x = c.i;
    unsigned int lsb = (x >> 16) & 1u;
    x += 0x7fffu + lsb;
    return (ushort_t)(x >> 16);
}
__device__ __forceinline__ float sigm(float x) { return 1.f / (1.f + __expf(-x)); }
__device__ __forceinline__ float tanh_f(float x) { return 1.f - 2.f / (__expf(2.f * x) + 1.f); }

#define MFMA16(a, b, c) __builtin_amdgcn_mfma_f32_16x16x32_bf16((a), (b), (c), 0, 0, 0)

// ---------------- fp32 -> bf16 weight conversion (Wih x4, Wout) ----------------
struct CvtArgs {
    const float* s[5];
    ushort_t* d[5];
    int n[5];
};
__global__ __launch_bounds__(256) void cvt_all(CvtArgs a)
{
    int y = blockIdx.y;
    const float* src = a.s[y];
    ushort_t* dst = a.d[y];
    int n = a.n[y];
    int i = (blockIdx.x * 256 + threadIdx.x) * 4;
    if (i < n) {
        float4 v = *(const float4*)(src + i);
        ushort_t o[4] = { f2bf(v.x), f2bf(v.y), f2bf(v.z), f2bf(v.w) };
        *(uint2*)(dst + i) = *(uint2*)o;
    }
}

// ---------------- fp32 -> fp8 e4m3 (OCP) conversion for Whh x4 ----------------
struct Cvt8Args {
    const float* s[4];
    uint_t* d[4];
};
__global__ __launch_bounds__(256) void cvt_fp8(Cvt8Args a)   // each matrix 262144 elems
{
    int y = blockIdx.y;
    const float* src = a.s[y];
    uint_t* dst = a.d[y];
    int i = blockIdx.x * 256 + threadIdx.x;      // word index, 65536 per matrix
    float4 v = *(const float4*)(src + i * 4);
    uint_t p = (uint_t)__builtin_amdgcn_cvt_pk_fp8_f32(v.x, v.y, 0, false);
    p = (uint_t)__builtin_amdgcn_cvt_pk_fp8_f32(v.z, v.w, (int)p, true);
    dst[i] = p;
}

// ---------------- embedding gather (fp32 -> bf16) + mask output ----------------
__global__ __launch_bounds__(64) void embed_kernel(
    const int* __restrict__ sent, const float* __restrict__ embed,
    ushort_t* __restrict__ emb, float* __restrict__ mask_out)
{
    int blk = blockIdx.x;             // b*T + t
    int b = blk >> 8, t = blk & 255;
    int s = sent[blk];
    int tid = threadIdx.x;            // 64 threads x 4 elems
    float4 v = *(const float4*)(embed + (size_t)s * Ez + tid * 4);
    ushort_t o[4] = { f2bf(v.x), f2bf(v.y), f2bf(v.z), f2bf(v.w) };
    *(uint2*)(emb + ((size_t)t * Bz + b) * Ez + tid * 4) = *(uint2*)o;
    if (tid == 0) mask_out[blk] = (s != 0) ? 1.0f : 0.0f;
}

// ---------------- input-projection GEMM: C = A @ W^T + bias ----------------
// Output stored INTERLEAVED: cI = (unit)*4 + gate, so the LSTM update reads one
// cell's 4 gate-preacts as a contiguous 8B word.
__global__ __launch_bounds__(256) void gemm_xproj(
    const ushort_t* __restrict__ A,                                      // (M, Kd) bf16
    const ushort_t* __restrict__ Wf, const ushort_t* __restrict__ Wb,    // (1024, Kd) bf16
    const float* __restrict__ biasf, const float* __restrict__ biasb,    // (1024,) fp32
    ushort_t* __restrict__ Cf, ushort_t* __restrict__ Cb,                // (M, 1024) bf16, interleaved
    int M, int Kd)
{
    const ushort_t* W = blockIdx.z ? Wb : Wf;
    const float* bias = blockIdx.z ? biasb : biasf;
    ushort_t* C = blockIdx.z ? Cb : Cf;
    int m0 = blockIdx.x * 64, n0 = blockIdx.y * 64;
    int tid = threadIdx.x, l = tid & 63, w = tid >> 6;
    int mw = m0 + (w & 1) * 32, nw = n0 + (w >> 1) * 32;
    int lr = l & 15, lq = l >> 4;
    f32x4 acc[2][2] = {};
    for (int ko = 0; ko < Kd; ko += 32) {
        short8 a0 = *(const short8*)(A + (size_t)(mw + lr) * Kd + ko + lq * 8);
        short8 a1 = *(const short8*)(A + (size_t)(mw + 16 + lr) * Kd + ko + lq * 8);
        short8 b0 = *(const short8*)(W + (size_t)(nw + lr) * Kd + ko + lq * 8);
        short8 b1 = *(const short8*)(W + (size_t)(nw + 16 + lr) * Kd + ko + lq * 8);
        acc[0][0] = MFMA16(a0, b0, acc[0][0]);
        acc[0][1] = MFMA16(a0, b1, acc[0][1]);
        acc[1][0] = MFMA16(a1, b0, acc[1][0]);
        acc[1][1] = MFMA16(a1, b1, acc[1][1]);
    }
    for (int mt = 0; mt < 2; mt++)
        for (int nt = 0; nt < 2; nt++)
            for (int r = 0; r < 4; r++) {
                int row = mw + mt * 16 + lq * 4 + r;
                int col = nw + nt * 16 + lr;
                float v = acc[mt][nt][r] + bias[col];
                int colI = ((col & 255) << 2) | (col >> 8);    // interleave (u,g)
                C[(size_t)row * G4 + colI] = f2bf(v);
            }
}

// ---------------- LSTM recurrence: ONE block per direction, zero global sync ----------------
// 2 blocks x 512 threads (8 waves). Batches are independent; units couple only
// within the block via LDS. Whh held in REGISTERS as fp8 e4m3 (128 VGPR/thread):
// wave w owns 32 units = 128 interleaved gate cols (cI = u*4+g). h state lives in
// a double-buffered fp8 LDS array sH8; ONE __syncthreads per step.
// Per step: Xp loads (prefetched pre-barrier) -> barrier -> 128 fp8 MFMAs/wave ->
// bf16 LDS gate transpose (wave-local) -> 16 cells/lane update -> write h(s+1)
// into the other sH8 buffer + bf16 hcat store. fp8 touches only the h@Whh term;
// gate error ~0.03 abs vs 9.76 threshold.
__global__ __launch_bounds__(512, 2) void lstm_layer(
    const ull_t* __restrict__ Whh8_f, const ull_t* __restrict__ Whh8_b,   // fp8 (1024 rows x 256), 32 ull/row
    const ushort_t* __restrict__ Xp_f, const ushort_t* __restrict__ Xp_b, // (T*B, 1024) bf16 interleaved
    const int* __restrict__ lengths,
    ushort_t* __restrict__ hcat)                                          // (T*B, 512) bf16
{
    __shared__ uint_t  sH8[2][Bz][66];        // fp8 h: [buf][batch][unit/4], row pad 66 (16.9 KB)
    __shared__ ushort_t sG[8][Bz][132];       // per-wave bf16 gate scratch (67.6 KB)

    int dir = blockIdx.x;
    const ull_t* W8 = dir ? Whh8_b : Whh8_f;
    const ushort_t* Xp = dir ? Xp_b : Xp_f;
    int tid = threadIdx.x, l = tid & 63, w = tid >> 6;
    int lr = l & 15, lq = l >> 4;

    // B fragments resident: 8 col-tiles x 8 k-steps x 8 fp8 = 128 VGPRs
    ull_t bw[8][8];
    #pragma unroll
    for (int ct = 0; ct < 8; ct++) {
        int cI = w * 128 + ct * 16 + lr;                 // interleaved col
        int row = (cI & 3) * Hz + (cI >> 2);             // Whh row = gate*256 + unit
        const ull_t* p = W8 + (size_t)row * 32;
        #pragma unroll
        for (int k = 0; k < 8; k++) bw[ct][k] = p[k * 4 + lq];
    }

    for (int i = tid; i < 2 * Bz * 66; i += 512) ((uint_t*)sH8)[i] = 0;

    int b = l & 31, half = l >> 5;
    int lenb = lengths[b];
    float c16[16];
    #pragma unroll
    for (int j = 0; j < 16; j++) c16[j] = 0.f;
    size_t hcbase = (size_t)dir * Hz + w * 32 + half * 16;

    for (int s = 0; s < Tz; s++) {
        int t = dir ? (Tz - 1 - s) : s;

        // Xp for this lane's 16 cells: 64 consecutive bf16 (interleaved layout)
        const uint4* xq = (const uint4*)(Xp + ((size_t)t * Bz + b) * G4 + w * 128 + half * 64);
        uint4 xp8v[8];
        #pragma unroll
        for (int i = 0; i < 8; i++) xp8v[i] = xq[i];

        const uint_t (*sa)[66] = sH8[s & 1];
        uint_t (*sb)[66] = sH8[(s + 1) & 1];

        __syncthreads();   // orders prior step's sH writes; one barrier per step

        // ---- MFMA: 2 batch-tiles sequential (acc reuse), 8 col-tiles each ----
        #pragma unroll
        for (int bt = 0; bt < 2; bt++) {
            f32x4 acc[8] = {};
            const ull_t* ap = (const ull_t*)sa[bt * 16 + lr];
            #pragma unroll
            for (int k = 0; k < 8; k++) {
                ull_t a = ap[k * 4 + lq];
                #pragma unroll
                for (int ct = 0; ct < 8; ct++)
                    acc[ct] = __builtin_amdgcn_mfma_f32_16x16x32_fp8_fp8(
                        (long)a, (long)bw[ct][k], acc[ct], 0, 0, 0);
            }
            #pragma unroll
            for (int ct = 0; ct < 8; ct++)
                #pragma unroll
                for (int r = 0; r < 4; r++)
                    sG[w][bt * 16 + lq * 4 + r][ct * 16 + lr] = f2bf(acc[ct][r]);
        }
        asm volatile("s_waitcnt lgkmcnt(0)" ::: "memory");   // wave-local sG ordering

        // ---- cell update: 16 cells/lane (batch b, units w*32+half*16 .. +16) ----
        int msk = (t < lenb);
        #pragma unroll
        for (int qd = 0; qd < 4; qd++) {
            ushort_t hcq[4];
            float hq[4];
            #pragma unroll
            for (int j2 = 0; j2 < 4; j2++) {
                int j = qd * 4 + j2;
                ull_t g4 = *(const ull_t*)&sG[w][b][(half * 16 + j) * 4];
                uint_t xlo = (j & 1) ? xp8v[j >> 1].z : xp8v[j >> 1].x;
                uint_t xhi = (j & 1) ? xp8v[j >> 1].w : xp8v[j >> 1].y;
                float gi = bf2f((ushort_t)(g4 >> 0))  + bf2f((ushort_t)(xlo & 0xffff));
                float gf = bf2f((ushort_t)(g4 >> 16)) + bf2f((ushort_t)(xlo >> 16));
                float gg = bf2f((ushort_t)(g4 >> 32)) + bf2f((ushort_t)(xhi & 0xffff));
                float go = bf2f((ushort_t)(g4 >> 48)) + bf2f((ushort_t)(xhi >> 16));
                float c2 = sigm(gf) * c16[j] + sigm(gi) * tanh_f(gg);
                float h2 = sigm(go) * tanh_f(c2);
                if (msk) c16[j] = c2;
                hq[j2] = h2;
                hcq[j2] = msk ? f2bf(h2) : (ushort_t)0;
            }
            uint_t new8 = (uint_t)__builtin_amdgcn_cvt_pk_fp8_f32(hq[0], hq[1], 0, false);
            new8 = (uint_t)__builtin_amdgcn_cvt_pk_fp8_f32(hq[2], hq[3], (int)new8, true);
            int hidx = w * 8 + half * 4 + qd;
            uint_t old8 = sa[b][hidx];
            sb[b][hidx] = msk ? new8 : old8;
            ull_t wc; __builtin_memcpy(&wc, hcq, 8);
            *(ull_t*)(hcat + ((size_t)t * Bz + b) * H2 + hcbase + qd * 4) = wc;
        }
    }
}

// ---------------- emit GEMM: (8192,512) @ Wout(48,512)^T + bout -> fp32 out[b][t][k] ----------------
__global__ __launch_bounds__(256) void gemm_emit(
    const ushort_t* __restrict__ A, const ushort_t* __restrict__ Wout,
    const float* __restrict__ bout, float* __restrict__ emit_out)
{
    int tid = threadIdx.x, l = tid & 63, w = tid >> 6;
    int m0 = blockIdx.x * 64 + w * 16;
    int lr = l & 15, lq = l >> 4;
    f32x4 acc[3] = {};
    for (int ko = 0; ko < H2; ko += 32) {
        short8 a = *(const short8*)(A + (size_t)(m0 + lr) * H2 + ko + lq * 8);
        #pragma unroll
        for (int nt = 0; nt < 3; nt++) {
            short8 bfr = *(const short8*)(Wout + (size_t)(nt * 16 + lr) * H2 + ko + lq * 8);
            acc[nt] = MFMA16(a, bfr, acc[nt]);
        }
    }
    #pragma unroll
    for (int nt = 0; nt < 3; nt++)
        #pragma unroll
        for (int r = 0; r < 4; r++) {
            int row = m0 + lq * 4 + r;            // t*B + b
            int col = nt * 16 + lr;
            float v = acc[nt][r] + bout[col];
            int t = row >> 5, b = row & 31;
            emit_out[((size_t)b * Tz + t) * Kz + col] = v;
        }
}

// ---------------- CRF numerator ----------------
__global__ __launch_bounds__(256) void crf_num(
    const float* __restrict__ emit, const int* __restrict__ sent,
    const int* __restrict__ tags, const int* __restrict__ lengths,
    const float* __restrict__ trans, const float* __restrict__ start_t,
    const float* __restrict__ end_t, float* __restrict__ num)
{
    __shared__ float red[4];
    int b = blockIdx.x, t = threadIdx.x;
    int tg = tags[b * Tz + t];
    float term;
    if (t == 0) {
        term = start_t[tg] + emit[(size_t)b * Tz * Kz + tg];
        int len = lengths[b];
        term += end_t[tags[b * Tz + len - 1]];
    } else if (sent[b * Tz + t] != 0) {
        int tp = tags[b * Tz + t - 1];
        term = trans[tp * Kz + tg] + emit[((size_t)b * Tz + t) * Kz + tg];
    } else term = 0.f;
    #pragma unroll
    for (int off = 1; off < 64; off <<= 1) term += __shfl_xor(term, off);
    int w = t >> 6;
    if ((t & 63) == 0) red[w] = term;
    __syncthreads();
    if (t == 0) num[b] = red[0] + red[1] + red[2] + red[3];
}

// ---------------- CRF denominator (forward algorithm), one wave per batch ----------------
__global__ __launch_bounds__(64) void crf_den(
    const float* __restrict__ emit, const int* __restrict__ lengths,
    const float* __restrict__ trans, const float* __restrict__ start_t,
    const float* __restrict__ end_t, float* __restrict__ den)
{
    __shared__ float sT[Kz * Kz];     // [i*48 + l]
    __shared__ float sS[Kz];
    int b = blockIdx.x, l = threadIdx.x;
    for (int i = l; i < Kz * Kz; i += 64) sT[i] = trans[i];
    int len = lengths[b];
    bool act = l < Kz;
    float s = act ? (start_t[l] + emit[(size_t)b * Tz * Kz + l]) : -1e30f;
    for (int t = 1; t < len; t++) {
        float em = act ? emit[((size_t)b * Tz + t) * Kz + l] : 0.f;
        if (act) sS[l] = s;
        float M = s;
        #pragma unroll
        for (int off = 1; off < 64; off <<= 1) M = fmaxf(M, __shfl_xor(M, off));
        float a0 = 0.f, a1 = 0.f, a2 = 0.f, a3 = 0.f;
        #pragma unroll 4
        for (int i = 0; i < Kz; i += 4) {
            a0 += __expf(sS[i]     + sT[i * Kz + l]       - M);
            a1 += __expf(sS[i + 1] + sT[(i + 1) * Kz + l] - M);
            a2 += __expf(sS[i + 2] + sT[(i + 2) * Kz + l] - M);
            a3 += __expf(sS[i + 3] + sT[(i + 3) * Kz + l] - M);
        }
        float sum = (a0 + a1) + (a2 + a3);
        if (act) s = em + M + __logf(sum);
    }
    float v = act ? (s + end_t[l]) : -1e30f;
    float M = v;
    #pragma unroll
    for (int off = 1; off < 64; off <<= 1) M = fmaxf(M, __shfl_xor(M, off));
    float accv = act ? __expf(v - M) : 0.f;
    #pragma unroll
    for (int off = 1; off < 64; off <<= 1) accv += __shfl_xor(accv, off);
    if (l == 0) den[b] = M + __logf(accv);
}

// ---------------- final loss ----------------
__global__ __launch_bounds__(64) void crf_loss(
    const float* __restrict__ num, const float* __restrict__ den, float* __restrict__ out)
{
    int l = threadIdx.x;
    float v = (l < Bz) ? (num[l] - den[l]) : 0.f;
    #pragma unroll
    for (int off = 1; off < 64; off <<= 1) v += __shfl_xor(v, off);
    if (l == 0) out[0] = v / (float)Bz;
}

extern "C" void kernel_launch(void* const* d_in, const int* in_sizes, int n_in,
                              void* d_out, int out_size, void* d_ws, size_t ws_size,
                              hipStream_t stream) {
    const int* sent      = (const int*)d_in[0];
    const int* lengths   = (const int*)d_in[1];
    const int* tags      = (const int*)d_in[2];
    const float* embed   = (const float*)d_in[3];
    const float* Wih0f = (const float*)d_in[4];
    const float* Whh0f = (const float*)d_in[5];
    const float* b0f   = (const float*)d_in[6];
    const float* Wih0b = (const float*)d_in[7];
    const float* Whh0b = (const float*)d_in[8];
    const float* b0b   = (const float*)d_in[9];
    const float* Wih1f = (const float*)d_in[10];
    const float* Whh1f = (const float*)d_in[11];
    const float* b1f   = (const float*)d_in[12];
    const float* Wih1b = (const float*)d_in[13];
    const float* Whh1b = (const float*)d_in[14];
    const float* b1b   = (const float*)d_in[15];
    const float* Wout  = (const float*)d_in[16];
    const float* bout  = (const float*)d_in[17];
    const float* start_t = (const float*)d_in[18];
    const float* end_t   = (const float*)d_in[19];
    const float* trans   = (const float*)d_in[20];

    char* ws = (char*)d_ws;
    ushort_t* Xp_f  = (ushort_t*)(ws);                        // 16 MB
    ushort_t* Xp_b  = (ushort_t*)(ws + 16777216);             // 16 MB
    ushort_t* hcat  = (ushort_t*)(ws + 33554432);             // 8 MB
    ushort_t* emb   = (ushort_t*)(ws + 41943040);             // 4 MB
    ushort_t* Wih0f_c = (ushort_t*)(ws + 46137344);           // 512 KB
    ushort_t* Wih0b_c = (ushort_t*)(ws + 46661632);           // 512 KB
    ushort_t* Wih1f_c = (ushort_t*)(ws + 47185920);           // 1 MB
    ushort_t* Wih1b_c = (ushort_t*)(ws + 48234496);           // 1 MB
    ushort_t* Wout_c  = (ushort_t*)(ws + 49283072);           // 48 KB
    uint_t* Whh8_0f = (uint_t*)(ws + 49332224);               // 256 KB each (fp8)
    uint_t* Whh8_0b = (uint_t*)(ws + 49594368);
    uint_t* Whh8_1f = (uint_t*)(ws + 49856512);
    uint_t* Whh8_1b = (uint_t*)(ws + 50118656);
    float*  num   = (float*)(ws + 50380800);
    float*  den   = (float*)(ws + 50381056);

    float* out      = (float*)d_out;                          // emit [B][T][K]
    float* loss_out = out + (size_t)Bz * Tz * Kz;             // 393216
    float* mask_out = loss_out + 1;                           // (B,T)

    CvtArgs ca;
    ca.s[0] = Wih0f; ca.d[0] = Wih0f_c; ca.n[0] = 262144;
    ca.s[1] = Wih0b; ca.d[1] = Wih0b_c; ca.n[1] = 262144;
    ca.s[2] = Wih1f; ca.d[2] = Wih1f_c; ca.n[2] = 524288;
    ca.s[3] = Wih1b; ca.d[3] = Wih1b_c; ca.n[3] = 524288;
    ca.s[4] = Wout;  ca.d[4] = Wout_c;  ca.n[4] = 24576;
    cvt_all<<<dim3(512, 5), 256, 0, stream>>>(ca);

    Cvt8Args c8;
    c8.s[0] = Whh0f; c8.d[0] = Whh8_0f;
    c8.s[1] = Whh0b; c8.d[1] = Whh8_0b;
    c8.s[2] = Whh1f; c8.d[2] = Whh8_1f;
    c8.s[3] = Whh1b; c8.d[3] = Whh8_1b;
    cvt_fp8<<<dim3(256, 4), 256, 0, stream>>>(c8);

    embed_kernel<<<Bz * Tz, 64, 0, stream>>>(sent, embed, emb, mask_out);

    gemm_xproj<<<dim3(Tz * Bz / 64, G4 / 64, 2), 256, 0, stream>>>(
        emb, Wih0f_c, Wih0b_c, b0f, b0b, Xp_f, Xp_b, Tz * Bz, Ez);

    lstm_layer<<<2, 512, 0, stream>>>((const ull_t*)Whh8_0f, (const ull_t*)Whh8_0b,
                                      Xp_f, Xp_b, lengths, hcat);

    gemm_xproj<<<dim3(Tz * Bz / 64, G4 / 64, 2), 256, 0, stream>>>(
        hcat, Wih1f_c, Wih1b_c, b1f, b1b, Xp_f, Xp_b, Tz * Bz, H2);

    lstm_layer<<<2, 512, 0, stream>>>((const ull_t*)Whh8_1f, (const ull_t*)Whh8_1b,
                                      Xp_f, Xp_b, lengths, hcat);

    gemm_emit<<<Tz * Bz / 64, 256, 0, stream>>>(hcat, Wout_c, bout, out);

    crf_num<<<Bz, 256, 0, stream>>>(out, sent, tags, lengths, trans, start_t, end_t, num);
    crf_den<<<Bz, 64, 0, stream>>>(out, lengths, trans, start_t, end_t, den);
    crf_loss<<<1, 64, 0, stream>>>(num, den, loss_out);
}